// Round 2
// baseline (77.024 us; speedup 1.0000x reference)
//
#include <hip/hip_runtime.h>

// Flux-conserving rebin: out[n,k] = sum_m flux[n,m] * overlap(k,m) / dout[k].
// Output grid is ~3.92x coarser than input grid -> each output bin overlaps
// at most 5 input bins (MAXW=6 for safety margin). One thread per output bin,
// NPB spectra per block to amortize the weight computation.

#define MAXW 6
#define NPB  8

__device__ __forceinline__ float edge_at(const float* __restrict__ wl, int n, int m) {
    // bin edges: midpoints, extrapolated half a bin at the ends. m in [0, n].
    if (m <= 0) return wl[0] - 0.5f * (wl[1] - wl[0]);
    if (m >= n) return wl[n - 1] + 0.5f * (wl[n - 1] - wl[n - 2]);
    return 0.5f * (wl[m - 1] + wl[m]);
}

__global__ __launch_bounds__(256) void rebin_kernel(
    const float* __restrict__ wl_in, const float* __restrict__ flux_in,
    const float* __restrict__ wl_out, float* __restrict__ out,
    int M, int K, int N)
{
    int k = blockIdx.x * blockDim.x + threadIdx.x;
    if (k >= K) return;

    float eo_lo = edge_at(wl_out, K, k);
    float eo_hi = edge_at(wl_out, K, k + 1);
    float inv_d = 1.0f / (eo_hi - eo_lo);

    // first input bin m with edge_in(m+1) > eo_lo  (binary search over edges)
    int lo = 0, hi = M;
    while (lo < hi) {
        int mid = (lo + hi) >> 1;
        if (edge_at(wl_in, M, mid + 1) <= eo_lo) lo = mid + 1; else hi = mid;
    }
    int m0 = lo;

    float w[MAXW];
    int   mi[MAXW];
    #pragma unroll
    for (int j = 0; j < MAXW; ++j) {
        int m = m0 + j;
        float ww = 0.0f;
        if (m < M) {
            float a = edge_at(wl_in, M, m);
            float b = edge_at(wl_in, M, m + 1);
            ww = fmaxf(fminf(eo_hi, b) - fmaxf(eo_lo, a), 0.0f) * inv_d;
        }
        w[j]  = ww;
        mi[j] = (m < M) ? m : (M - 1);   // clamped index; weight is 0 past end
    }

    int n0   = blockIdx.y * NPB;
    int nend = min(n0 + NPB, N);
    for (int n = n0; n < nend; ++n) {
        const float* fr = flux_in + (size_t)n * M;
        float acc = 0.0f;
        #pragma unroll
        for (int j = 0; j < MAXW; ++j) acc = fmaf(fr[mi[j]], w[j], acc);
        out[(size_t)n * K + k] = acc;
    }
}

extern "C" void kernel_launch(void* const* d_in, const int* in_sizes, int n_in,
                              void* d_out, int out_size, void* d_ws, size_t ws_size,
                              hipStream_t stream) {
    const float* wl_in   = (const float*)d_in[0];
    const float* flux_in = (const float*)d_in[1];
    const float* wl_out  = (const float*)d_in[2];
    float* out = (float*)d_out;

    int M = in_sizes[0];              // 16384
    int K = in_sizes[2];              // 4096
    int N = in_sizes[1] / M;          // 256

    dim3 block(256);
    dim3 grid((K + 255) / 256, (N + NPB - 1) / NPB);
    rebin_kernel<<<grid, block, 0, stream>>>(wl_in, flux_in, wl_out, out, M, K, N);
}

// Round 5
// 73.342 us; speedup vs baseline: 1.0502x; 1.0502x over previous
//
#include <hip/hip_runtime.h>

// Flux-conserving rebin: out[n,k] = sum_m flux[n,m] * overlap(k,m) / dout[k].
// v2: no per-thread binary search (predict + O(1) fix-up on near-uniform grid),
// 4-aligned 8-wide weight window -> two aligned float4 flux loads per (n,k),
// static indexing throughout. Grid (16,128), NPB=2 -> 8 blocks/CU, full occ.

#define NPB 2

__device__ __forceinline__ float edge_at(const float* __restrict__ wl, int n, int m) {
    // bin edges: midpoints, extrapolated half a bin at the ends. m in [0, n].
    if (m <= 0) return wl[0] - 0.5f * (wl[1] - wl[0]);
    if (m >= n) return wl[n - 1] + 0.5f * (wl[n - 1] - wl[n - 2]);
    return 0.5f * (wl[m - 1] + wl[m]);
}

__global__ __launch_bounds__(256) void rebin_v2_kernel(
    const float* __restrict__ wl_in, const float* __restrict__ flux_in,
    const float* __restrict__ wl_out, float* __restrict__ out,
    int M, int K, int N)
{
    int k = blockIdx.x * blockDim.x + threadIdx.x;
    if (k >= K) return;

    float eo_lo = edge_at(wl_out, K, k);
    float eo_hi = edge_at(wl_out, K, k + 1);
    float inv_d = 1.0f / (eo_hi - eo_lo);

    // Predict first input bin m0 with edge_in(m0) <= eo_lo < edge_in(m0+1),
    // assuming near-uniform spacing; fix up generally (O(1) on uniform grids).
    float w0 = wl_in[0];
    float e0 = w0 - 0.5f * (wl_in[1] - w0);
    float spacing = (wl_in[M - 1] - w0) / (float)(M - 1);
    int m0 = (int)floorf((eo_lo - e0) / spacing);
    m0 = max(0, min(M - 1, m0));
    while (m0 > 0 && edge_at(wl_in, M, m0) > eo_lo) --m0;
    while (m0 < M - 1 && edge_at(wl_in, M, m0 + 1) <= eo_lo) ++m0;

    // 4-aligned 8-element window covers taps m0..m0+5 (<=6 overlapping bins).
    int abase = m0 & ~3;

    float wa[8];
    float e_prev = edge_at(wl_in, M, abase);
    #pragma unroll
    for (int t = 0; t < 8; ++t) {
        float e_next = edge_at(wl_in, M, abase + t + 1);
        float ov = fminf(eo_hi, e_next) - fmaxf(eo_lo, e_prev);
        wa[t] = fmaxf(ov, 0.0f) * inv_d;
        e_prev = e_next;
    }

    int n0   = blockIdx.y * NPB;
    int nend = min(n0 + NPB, N);
    bool fast = (abase + 8 <= M);
    for (int n = n0; n < nend; ++n) {
        const float* fr = flux_in + (size_t)n * M;
        float acc;
        if (fast) {
            float4 f0 = *reinterpret_cast<const float4*>(fr + abase);
            float4 f1 = *reinterpret_cast<const float4*>(fr + abase + 4);
            acc = f0.x * wa[0];
            acc = fmaf(f0.y, wa[1], acc);
            acc = fmaf(f0.z, wa[2], acc);
            acc = fmaf(f0.w, wa[3], acc);
            acc = fmaf(f1.x, wa[4], acc);
            acc = fmaf(f1.y, wa[5], acc);
            acc = fmaf(f1.z, wa[6], acc);
            acc = fmaf(f1.w, wa[7], acc);
        } else {
            acc = 0.0f;
            #pragma unroll
            for (int t = 0; t < 8; ++t) {
                int idx = min(abase + t, M - 1);
                acc = fmaf(fr[idx], wa[t], acc);
            }
        }
        out[(size_t)n * K + k] = acc;
    }
}

extern "C" void kernel_launch(void* const* d_in, const int* in_sizes, int n_in,
                              void* d_out, int out_size, void* d_ws, size_t ws_size,
                              hipStream_t stream) {
    const float* wl_in   = (const float*)d_in[0];
    const float* flux_in = (const float*)d_in[1];
    const float* wl_out  = (const float*)d_in[2];
    float* out = (float*)d_out;

    int M = in_sizes[0];              // 16384
    int K = in_sizes[2];              // 4096
    int N = in_sizes[1] / M;          // 256

    dim3 block(256);
    dim3 grid((K + 255) / 256, (N + NPB - 1) / NPB);
    rebin_v2_kernel<<<grid, block, 0, stream>>>(wl_in, flux_in, wl_out, out, M, K, N);
}